// Round 1
// baseline (156.156 us; speedup 1.0000x reference)
//
#include <hip/hip_runtime.h>
#include <math.h>

// Match XLA's unfused mul/add rounding in the discrete-sensitive chains.
#pragma clang fp contract(off)

#define G_N 2048
#define P_N 16384
#define K_TOP 8
#define NCHUNK 8
#define CHUNK 256            // G_N / NCHUNK
#define GS 24                // floats per gaussian struct
#define S1OFF 16             // header: [0..2] lo, [3..5] hi, [6] med, [8..10] gmin, [11] voxel
#define S2OFF (S1OFF + G_N * 8)
#define CANDOFF (S2OFF + G_N * GS)
// candidates: per (point, chunk, slot): {val, idx-bits} interleaved -> P*NCHUNK*8*2 floats

__device__ __forceinline__ void quat_R(const float* __restrict__ quat, int g, float R[3][3]) {
    float q0 = quat[g * 4 + 0], q1 = quat[g * 4 + 1], q2 = quat[g * 4 + 2], q3 = quat[g * 4 + 3];
    float nrm = sqrtf(q0 * q0 + q1 * q1 + q2 * q2 + q3 * q3);
    float w = q0 / nrm, x = q1 / nrm, y = q2 / nrm, z = q3 / nrm;
    R[0][0] = 1.0f - 2.0f * (y * y + z * z);
    R[0][1] = 2.0f * (x * y - w * z);
    R[0][2] = 2.0f * (x * z + w * y);
    R[1][0] = 2.0f * (x * y + w * z);
    R[1][1] = 1.0f - 2.0f * (x * x + z * z);
    R[1][2] = 2.0f * (y * z - w * x);
    R[2][0] = 2.0f * (x * z - w * y);
    R[2][1] = 2.0f * (y * z + w * x);
    R[2][2] = 1.0f - 2.0f * (x * x + y * y);
}

// Stage 1: per-gaussian radius + bbox corners. ws[S1OFF + g*8] = {minc xyz, maxc xyz, radius_x, pad}
__global__ void k_stage1(const float* __restrict__ pos, const float* __restrict__ scl,
                         const float* __restrict__ quat, float* __restrict__ ws) {
    int g = blockIdx.x * blockDim.x + threadIdx.x;
    if (g >= G_N) return;
    float R[3][3];
    quat_R(quat, g, R);
    float sx = scl[g * 3 + 0], sy = scl[g * 3 + 1], sz = scl[g * 3 + 2];
    float s2x = sx * sx, s2y = sy * sy, s2z = sz * sz;
    float kchi = sqrtf(7.8147279f);
    float* o = ws + S1OFF + g * 8;
#pragma unroll
    for (int i = 0; i < 3; ++i) {
        float dc = (R[i][0] * R[i][0]) * s2x + (R[i][1] * R[i][1]) * s2y + (R[i][2] * R[i][2]) * s2z;
        float rad = kchi * sqrtf(dc);
        float p = pos[g * 3 + i];
        o[i] = p - rad;
        o[3 + i] = p + rad;
        if (i == 0) o[6] = rad;
    }
}

// Stage 2: 7 blocks, each bitonic-sorts one 2048-array in LDS and emits one order statistic.
// block 0-2: lo[a] = quantile(min_c[:,a], 0.01); 3-5: hi[a] = quantile(max_c[:,a], 0.99); 6: median(radius_x)
__global__ __launch_bounds__(1024) void k_sort(float* __restrict__ ws) {
    __shared__ float buf[G_N];
    int which = blockIdx.x;
    int tid = threadIdx.x;
    for (int i = tid; i < G_N; i += 1024) {
        const float* o = ws + S1OFF + i * 8;
        buf[i] = (which < 6) ? o[which] : o[6];
    }
    __syncthreads();
    for (int k = 2; k <= G_N; k <<= 1) {
        for (int j = k >> 1; j > 0; j >>= 1) {
            for (int i = tid; i < G_N; i += 1024) {
                int partner = i ^ j;
                if (partner > i) {
                    bool up = ((i & k) == 0);
                    float a = buf[i], b = buf[partner];
                    if ((a > b) == up) { buf[i] = b; buf[partner] = a; }
                }
            }
            __syncthreads();
        }
    }
    if (tid == 0) {
        float qq;
        if (which < 3) qq = 0.01f * 2047.0f;
        else if (which < 6) qq = 0.99f * 2047.0f;
        else qq = 0.5f * 2047.0f;
        int lo = (int)floorf(qq);
        float fr = qq - (float)lo;
        float res = buf[lo] * (1.0f - fr) + buf[lo + 1] * fr;
        ws[which] = res;
    }
}

// Stage 3: grid params (1 thread).
__global__ void k_grid(float* __restrict__ ws) {
    if (threadIdx.x == 0 && blockIdx.x == 0) {
        for (int a = 0; a < 3; ++a) {
            float lo = ws[a], hi = ws[3 + a];
            float size = hi - lo;
            ws[8 + a] = lo - 0.1f * size;
        }
        ws[11] = ws[6] * 3.0f;
    }
}

// Stage 4: per-gaussian struct: Cinv(9), b(3), c0, log_norm, grid_min(3), grid_max(3), oversized
__global__ void k_stage2(const float* __restrict__ pos, const float* __restrict__ scl,
                         const float* __restrict__ quat, float* __restrict__ ws) {
    int g = blockIdx.x * blockDim.x + threadIdx.x;
    if (g >= G_N) return;
    float gmn[3] = {ws[8], ws[9], ws[10]};
    float vox = ws[11];
    const float* o = ws + S1OFF + g * 8;
    float* s = ws + S2OFF + g * GS;
    int gmini[3], gmaxi[3];
    long long nv = 1;
#pragma unroll
    for (int a = 0; a < 3; ++a) {
        int lo = (int)floorf((o[a] - gmn[a]) / vox);
        int hi = (int)floorf((o[3 + a] - gmn[a]) / vox);
        lo = lo < 0 ? 0 : (lo > 1023 ? 1023 : lo);
        hi = hi < 0 ? 0 : (hi > 1023 ? 1023 : hi);
        gmini[a] = lo;
        gmaxi[a] = hi;
        nv *= (long long)(hi - lo + 1);
    }
    bool oversized = nv > 64;

    float R[3][3];
    quat_R(quat, g, R);
    float sx = scl[g * 3 + 0], sy = scl[g * 3 + 1], sz = scl[g * 3 + 2];
    float inv2[3] = {1.0f / (sx * sx), 1.0f / (sy * sy), 1.0f / (sz * sz)};
    float Cinv[3][3];
#pragma unroll
    for (int i = 0; i < 3; ++i) {
        float t0 = R[i][0] * inv2[0], t1 = R[i][1] * inv2[1], t2 = R[i][2] * inv2[2];
#pragma unroll
        for (int k = 0; k < 3; ++k)
            Cinv[i][k] = t0 * R[k][0] + t1 * R[k][1] + t2 * R[k][2];
    }
    float px = pos[g * 3 + 0], py = pos[g * 3 + 1], pz = pos[g * 3 + 2];
    float b0 = Cinv[0][0] * px + Cinv[0][1] * py + Cinv[0][2] * pz;
    float b1 = Cinv[1][0] * px + Cinv[1][1] * py + Cinv[1][2] * pz;
    float b2 = Cinv[2][0] * px + Cinv[2][1] * py + Cinv[2][2] * pz;
    float c0 = b0 * px + b1 * py + b2 * pz;
    float log_norm = -2.7568155996140179f - (logf(sx) + logf(sy) + logf(sz));

    s[0] = Cinv[0][0]; s[1] = Cinv[0][1]; s[2] = Cinv[0][2];
    s[3] = Cinv[1][0]; s[4] = Cinv[1][1]; s[5] = Cinv[1][2];
    s[6] = Cinv[2][0]; s[7] = Cinv[2][1]; s[8] = Cinv[2][2];
    s[9] = b0; s[10] = b1; s[11] = b2;
    s[12] = c0;
    s[13] = log_norm;
    s[14] = __int_as_float(gmini[0]); s[15] = __int_as_float(gmini[1]); s[16] = __int_as_float(gmini[2]);
    s[17] = __int_as_float(gmaxi[0]); s[18] = __int_as_float(gmaxi[1]); s[19] = __int_as_float(gmaxi[2]);
    s[20] = oversized ? 1.0f : 0.0f;
    s[21] = 0.0f; s[22] = 0.0f; s[23] = 0.0f;
}

// Stage 5: scoring. grid = (P/256, NCHUNK); block handles 256 points x 256-gaussian chunk (in LDS).
__global__ __launch_bounds__(256) void k_score(const float* __restrict__ pts, float* __restrict__ ws) {
    __shared__ float lg[CHUNK * GS];
    int c = blockIdx.y;
    const float* gsrc = ws + S2OFF + c * CHUNK * GS;
    for (int i = threadIdx.x; i < CHUNK * GS; i += 256) lg[i] = gsrc[i];
    __syncthreads();

    int p = blockIdx.x * 256 + threadIdx.x;
    float px = pts[p * 3 + 0], py = pts[p * 3 + 1], pz = pts[p * 3 + 2];
    float gm0 = ws[8], gm1 = ws[9], gm2 = ws[10], vox = ws[11];
    int pvx = (int)floorf((px - gm0) / vox);
    int pvy = (int)floorf((py - gm1) / vox);
    int pvz = (int)floorf((pz - gm2) / vox);
    float pp0 = px * px, pp1 = px * py, pp2 = px * pz;
    float pp4 = py * py, pp5 = py * pz, pp8 = pz * pz;

    float tv[K_TOP];
    int ti[K_TOP];
#pragma unroll
    for (int j = 0; j < K_TOP; ++j) { tv[j] = -INFINITY; ti[j] = 0x7fffffff; }

    for (int k = 0; k < CHUNK; ++k) {
        const float* s = lg + k * GS;
        int g0 = __float_as_int(s[14]), g1 = __float_as_int(s[15]), g2 = __float_as_int(s[16]);
        int h0 = __float_as_int(s[17]), h1 = __float_as_int(s[18]), h2 = __float_as_int(s[19]);
        bool inb = (pvx >= g0) & (pvx <= h0) & (pvy >= g1) & (pvy <= h1) & (pvz >= g2) & (pvz <= h2);
        bool mask = inb || (s[20] != 0.0f);
        if (!mask) continue;
        float s1 = pp0 * s[0] + pp1 * s[1] + pp2 * s[2]
                 + pp1 * s[3] + pp4 * s[4] + pp5 * s[5]
                 + pp2 * s[6] + pp5 * s[7] + pp8 * s[8];
        float d = px * s[9] + py * s[10] + pz * s[11];
        float quad = s1 - 2.0f * d + s[12];
        float sc = s[13] - 0.5f * quad;
        if (sc > tv[K_TOP - 1]) {
            tv[K_TOP - 1] = sc;
            ti[K_TOP - 1] = c * CHUNK + k;
#pragma unroll
            for (int j = K_TOP - 1; j > 0; --j) {
                if (tv[j] > tv[j - 1]) {
                    float fv = tv[j]; tv[j] = tv[j - 1]; tv[j - 1] = fv;
                    int iv = ti[j]; ti[j] = ti[j - 1]; ti[j - 1] = iv;
                }
            }
        }
    }

    float* cv = ws + CANDOFF + ((size_t)(p * NCHUNK + c) * K_TOP) * 2;
#pragma unroll
    for (int j = 0; j < K_TOP; ++j) {
        cv[j * 2] = tv[j];
        cv[j * 2 + 1] = __int_as_float(ti[j]);
    }
}

// Stage 6: merge NCHUNK candidate lists per point; write ids (as float values) then probs.
__global__ __launch_bounds__(256) void k_merge(const float* __restrict__ ws, float* __restrict__ out) {
    int p = blockIdx.x * 256 + threadIdx.x;
    if (p >= P_N) return;
    float tv[K_TOP];
    int ti[K_TOP];
#pragma unroll
    for (int j = 0; j < K_TOP; ++j) { tv[j] = -INFINITY; ti[j] = 0x7fffffff; }
    const float* cv = ws + CANDOFF + (size_t)p * NCHUNK * K_TOP * 2;
    for (int c = 0; c < NCHUNK; ++c) {
        for (int j = 0; j < K_TOP; ++j) {
            float v = cv[(c * K_TOP + j) * 2];
            int idx = __float_as_int(cv[(c * K_TOP + j) * 2 + 1]);
            bool better = (v > tv[K_TOP - 1]) || (v == tv[K_TOP - 1] && idx < ti[K_TOP - 1]);
            if (better) {
                tv[K_TOP - 1] = v;
                ti[K_TOP - 1] = idx;
#pragma unroll
                for (int t = K_TOP - 1; t > 0; --t) {
                    bool sw = (tv[t] > tv[t - 1]) || (tv[t] == tv[t - 1] && ti[t] < ti[t - 1]);
                    if (sw) {
                        float fv = tv[t]; tv[t] = tv[t - 1]; tv[t - 1] = fv;
                        int iv = ti[t]; ti[t] = ti[t - 1]; ti[t - 1] = iv;
                    }
                }
            }
        }
    }
#pragma unroll
    for (int j = 0; j < K_TOP; ++j) {
        bool fin = tv[j] > -INFINITY;
        out[p * K_TOP + j] = fin ? (float)ti[j] : -1.0f;
        out[P_N * K_TOP + p * K_TOP + j] = fin ? expf(tv[j]) : 0.0f;
    }
}

extern "C" void kernel_launch(void* const* d_in, const int* in_sizes, int n_in,
                              void* d_out, int out_size, void* d_ws, size_t ws_size,
                              hipStream_t stream) {
    const float* pos = (const float*)d_in[0];
    const float* scl = (const float*)d_in[1];
    const float* quat = (const float*)d_in[2];
    const float* pts = (const float*)d_in[3];
    float* ws = (float*)d_ws;
    float* out = (float*)d_out;

    k_stage1<<<dim3(G_N / 256), dim3(256), 0, stream>>>(pos, scl, quat, ws);
    k_sort<<<dim3(7), dim3(1024), 0, stream>>>(ws);
    k_grid<<<dim3(1), dim3(1), 0, stream>>>(ws);
    k_stage2<<<dim3(G_N / 256), dim3(256), 0, stream>>>(pos, scl, quat, ws);
    k_score<<<dim3(P_N / 256, NCHUNK), dim3(256), 0, stream>>>(pts, ws);
    k_merge<<<dim3(P_N / 256), dim3(256), 0, stream>>>(ws, out);
}